// Round 7
// baseline (356.932 us; speedup 1.0000x reference)
//
#include <hip/hip_runtime.h>
#include <hip/hip_bf16.h>
#include <stdint.h>

// Problem: B=32, N=512, C=16, D=O=256.  Flattened nodes = 16384.
// agg: row-major bf16 [16384][768]; k 0..255 = bf16 nodes (w_t part),
// k 256..511 = ar (w_r part), k 512..767 = al (w_l part).
// wsb: bf16 [slab][n][kw]  (24 x 256 x 32), k = slab*32+kw.
// One persistent kernel, 512 blocks x 256 threads, 2 grid barriers.
#define CC 16
#define OO 256
#define NSLAB 24
#define AGG_ELS (16384 * 768)            // 25,165,824 elements
#define NBLK 512

typedef __attribute__((ext_vector_type(8))) short bf16x8;
typedef __attribute__((ext_vector_type(4))) float f32x4;

__device__ __forceinline__ unsigned short f2bf(float x) {
    unsigned u = __builtin_bit_cast(unsigned, x);
    u += 0x7FFFu + ((u >> 16) & 1u);
    return (unsigned short)(u >> 16);
}

// single-use grid barrier (counter pre-zeroed by hipMemsetAsync each launch)
__device__ __forceinline__ void gbar(unsigned* c) {
    __threadfence();                     // release our writes device-wide
    __syncthreads();
    if (threadIdx.x == 0) {
        __hip_atomic_fetch_add(c, 1u, __ATOMIC_ACQ_REL, __HIP_MEMORY_SCOPE_AGENT);
        while (__hip_atomic_load(c, __ATOMIC_ACQUIRE, __HIP_MEMORY_SCOPE_AGENT) < NBLK)
            __builtin_amdgcn_s_sleep(2);
    }
    __syncthreads();
    __threadfence();                     // acquire: see other XCDs' writes
}

__global__ __launch_bounds__(256, 2) void tbcnn_fused(
    const float* __restrict__ nodes, const float* __restrict__ wt,
    const float* __restrict__ wrp, const float* __restrict__ wl,
    const float* __restrict__ conv, const int* __restrict__ children,
    unsigned short* __restrict__ agg, unsigned short* __restrict__ wsb,
    unsigned* __restrict__ bar, float* __restrict__ out) {

    __shared__ unsigned short T[256 * 40];       // weight transpose (20 KB)

    const int p   = blockIdx.x;
    const int tid = threadIdx.x;
    const int x   = p & 7;                       // XCD (heuristic %8 round-robin)
    const int q   = p >> 3;                      // 0..63 within XCD

    // ================= Phase A: prep =====================================
    // blocks 0..23 additionally transpose one weight K-slab into wsb
    if (p < 24) {
        const int slab = p;
        const int n = tid;                       // output col 0..255
#pragma unroll
        for (int kk = 0; kk < 32; ++kk) {
            const int k = slab * 32 + kk;        // 0..255 wt, 256..511 wr, 512..767 wl
            const float* s = (k < 256) ? wt : ((k < 512) ? wrp : wl);
            T[n * 40 + kk] = f2bf(s[(k & 255) * OO + n]);
        }
        __syncthreads();
        uint4* dst = (uint4*)(wsb + slab * 8192 + n * 32);
        const uint4* src = (const uint4*)&T[n * 40];
#pragma unroll
        for (int u = 0; u < 4; ++u) dst[u] = src[u];
    }
    // all blocks: 32 node rows fp32 -> bf16 into agg[:,0:256] (XCD-local rows)
    const int rowbase = x * 2048 + q * 32;
#pragma unroll
    for (int u = 0; u < 4; ++u) {
        const int unit = u * 256 + tid;          // 1024 units: row*32chunks
        const int r  = rowbase + (unit >> 5);
        const int ch = unit & 31;                // 8-element chunk
        const float4* s = (const float4*)(nodes + (size_t)r * 256 + ch * 8);
        float4 a = s[0], b = s[1];
        uint4 v;
        v.x = (unsigned)f2bf(a.x) | ((unsigned)f2bf(a.y) << 16);
        v.y = (unsigned)f2bf(a.z) | ((unsigned)f2bf(a.w) << 16);
        v.z = (unsigned)f2bf(b.x) | ((unsigned)f2bf(b.y) << 16);
        v.w = (unsigned)f2bf(b.z) | ((unsigned)f2bf(b.w) << 16);
        *(uint4*)(agg + (size_t)r * 768 + ch * 8) = v;
    }

    gbar(bar);                                   // barrier 1

    // ================= Phase B: gather + reduce ==========================
    const int wave = tid >> 6;
    const int lane = tid & 63;
    const int nbase = x * 2048 + q * 32 + wave * 8;
#pragma unroll 2
    for (int i = 0; i < 8; ++i) {
        const int nf = __builtin_amdgcn_readfirstlane(nbase + i);
        const int brow = nf & ~511;              // b*512
        const int* chp = children + (nf << 4);
        int cj[CC];
#pragma unroll
        for (int j = 0; j < CC; ++j) cj[j] = chp[j];     // scalar loads
        int ns = 0;
#pragma unroll
        for (int j = 0; j < CC; ++j) ns += (cj[j] != 0) ? 1 : 0;
        const float inv_den = (ns > 1) ? 1.0f / (float)(ns - 1) : 0.0f;
        const bool single = (ns == 1);

        uint2 ec[CC];                            // 16 child rows, 8 B/lane
#pragma unroll
        for (int j = 0; j < CC; ++j)
            ec[j] = *(const uint2*)(agg + (size_t)(brow + cj[j]) * 768 + lane * 4);

        float4 ar = make_float4(0.f, 0.f, 0.f, 0.f);
        float4 as = make_float4(0.f, 0.f, 0.f, 0.f);
#pragma unroll
        for (int j = 0; j < CC; ++j) {
            const float hasf = (cj[j] != 0) ? 1.0f : 0.0f;
            const float crr = single ? ((j == 0) ? 0.5f : 0.0f)
                                     : (float)j * inv_den;
            const float cr = crr * hasf;
            const float e0 = __builtin_bit_cast(float, ec[j].x << 16);
            const float e1 = __builtin_bit_cast(float, ec[j].x & 0xFFFF0000u);
            const float e2 = __builtin_bit_cast(float, ec[j].y << 16);
            const float e3 = __builtin_bit_cast(float, ec[j].y & 0xFFFF0000u);
            ar.x += cr * e0;   ar.y += cr * e1;   ar.z += cr * e2;   ar.w += cr * e3;
            as.x += hasf * e0; as.y += hasf * e1; as.z += hasf * e2; as.w += hasf * e3;
        }
        unsigned short* rowp = agg + (size_t)nf * 768;
        uint2 v;
        v.x = (unsigned)f2bf(ar.x) | ((unsigned)f2bf(ar.y) << 16);
        v.y = (unsigned)f2bf(ar.z) | ((unsigned)f2bf(ar.w) << 16);
        *(uint2*)(rowp + 256 + lane * 4) = v;                       // w_r part
        v.x = (unsigned)f2bf(as.x - ar.x) | ((unsigned)f2bf(as.y - ar.y) << 16);
        v.y = (unsigned)f2bf(as.z - ar.z) | ((unsigned)f2bf(as.w - ar.w) << 16);
        *(uint2*)(rowp + 512 + lane * 4) = v;                       // w_l part
    }

    gbar(bar + 64);                              // barrier 2 (separate line)

    // ================= Phase C: LDS-free MFMA GEMM + epilogue ============
    // block -> (mtile, ntile), XCD-aligned: mtile rows were produced on XCD x.
    const int mtile = x * 32 + (q >> 1);         // 0..255 (64 rows each)
    const int ntile = q & 1;                     // 128-col half
    const int wrr = wave >> 1;                   // M half (32 rows)
    const int wcc = wave & 1;                    // N half (64 cols)
    const int quad = lane >> 4;
    const int l16  = lane & 15;

    const unsigned short* aggA = agg + (size_t)mtile * 64 * 768;
    const unsigned short* wsN  = wsb + (ntile * 128 + wcc * 64) * 32;

    f32x4 acc[2][4];
#pragma unroll
    for (int mi = 0; mi < 2; ++mi)
#pragma unroll
        for (int ni = 0; ni < 4; ++ni)
            acc[mi][ni] = (f32x4){0.f, 0.f, 0.f, 0.f};

    // per-lane fragment base addresses (16 B per lane per fragment)
    const unsigned short* aA0 = aggA + (size_t)(wrr * 32 + l16) * 768 + quad * 8;
    const unsigned short* aA1 = aA0 + 16 * 768;
    const unsigned short* aB  = wsN + (size_t)l16 * 32 + quad * 8;

#pragma unroll 4
    for (int s = 0; s < NSLAB; ++s) {
        bf16x8 af[2], bf[4];
        af[0] = *(const bf16x8*)(aA0 + s * 32);
        af[1] = *(const bf16x8*)(aA1 + s * 32);
#pragma unroll
        for (int ni = 0; ni < 4; ++ni)
            bf[ni] = *(const bf16x8*)(aB + s * 8192 + ni * 16 * 32);
#pragma unroll
        for (int mi = 0; mi < 2; ++mi)
#pragma unroll
            for (int ni = 0; ni < 4; ++ni)
                acc[mi][ni] = __builtin_amdgcn_mfma_f32_16x16x32_bf16(
                    af[mi], bf[ni], acc[mi][ni], 0, 0, 0);
    }

#pragma unroll
    for (int ni = 0; ni < 4; ++ni) {
        const int col = ntile * 128 + wcc * 64 + ni * 16 + l16;
        const float cv = conv[col];
#pragma unroll
        for (int mi = 0; mi < 2; ++mi) {
#pragma unroll
            for (int r = 0; r < 4; ++r) {
                const int row = mtile * 64 + wrr * 32 + mi * 16 + quad * 4 + r;
                float v = acc[mi][ni][r] + cv;
                v = (v > 0.f) ? v : 0.01f * v;
                out[(size_t)row * OO + col] = v;
            }
        }
    }
}

extern "C" void kernel_launch(void* const* d_in, const int* in_sizes, int n_in,
                              void* d_out, int out_size, void* d_ws, size_t ws_size,
                              hipStream_t stream) {
    // setup_inputs order: nodes, w_t, w_l, w_r, conv, children
    const float* nodes    = (const float*)d_in[0];
    const float* w_t      = (const float*)d_in[1];
    const float* w_l      = (const float*)d_in[2];
    const float* w_r      = (const float*)d_in[3];
    const float* conv     = (const float*)d_in[4];
    const int*   children = (const int*)d_in[5];

    unsigned short* agg = (unsigned short*)d_ws;           // 50,331,648 B? no: 25,165,824*2B
    unsigned short* wsb = agg + AGG_ELS;                   // + 393,216 elements*2B
    unsigned* bar = (unsigned*)((char*)d_ws + (size_t)AGG_ELS * 2 + 768 * 256 * 2);

    // zero the two barrier counters (capture-legal memset node)
    hipMemsetAsync(bar, 0, 512, stream);
    tbcnn_fused<<<NBLK, 256, 0, stream>>>(nodes, w_t, w_r, w_l, conv, children,
                                          agg, wsb, bar, (float*)d_out);
}

// Round 8
// 108.784 us; speedup vs baseline: 3.2811x; 3.2811x over previous
//
#include <hip/hip_runtime.h>
#include <hip/hip_bf16.h>
#include <stdint.h>

// Problem: B=32, N=512, C=16, D=O=256.  Flattened nodes = 16384.
// nb : bf16 [16384][256]  (converted nodes; gather input + GEMM A k in [0,256))
// wsb: bf16 [slab][n][kw] (24 x 256 x 32), k = slab*32+kw;
//      k rows 0..255 = w_t, 256..511 = w_r, 512..767 = w_l.
// Fused kernel: per block (32 rows x 256 cols), gather -> LDS, MFMA from
// LDS (k>=256) + nb (k<256) + wsb. No cross-block deps => no barriers.
#define CC 16
#define OO 256
#define NSLAB 24
#define NB_ELS (16384 * 256)
#define A2STR 520            // 512 + 8 pad (bf16 units)

typedef __attribute__((ext_vector_type(8))) short bf16x8;
typedef __attribute__((ext_vector_type(4))) float f32x4;

__device__ __forceinline__ unsigned short f2bf(float x) {
    unsigned u = __builtin_bit_cast(unsigned, x);
    u += 0x7FFFu + ((u >> 16) & 1u);
    return (unsigned short)(u >> 16);
}

// ---------------------------------------------------------------------------
// Kernel 0: prep — nodes fp32 -> bf16 (nb, XCD-swizzled rows); weights -> wsb
// ---------------------------------------------------------------------------
__global__ __launch_bounds__(256) void prep(
    const float* __restrict__ nodes, const float* __restrict__ wt,
    const float* __restrict__ wrp, const float* __restrict__ wl,
    unsigned short* __restrict__ nb, unsigned short* __restrict__ wsb) {

    __shared__ unsigned short T[256 * 40];
    const int p = blockIdx.x;
    const int tid = threadIdx.x;

    if (p < 2048) {                       // 8 rows/block; XCD x owns [x*2048,+2048)
        const int pp = (p & 7) * 256 + (p >> 3);
        const size_t t = (size_t)pp * 256 + tid;   // 8 fp32 per thread
        const float4* s = (const float4*)nodes + t * 2;
        float4 a = s[0], b = s[1];
        uint4 u;
        u.x = (unsigned)f2bf(a.x) | ((unsigned)f2bf(a.y) << 16);
        u.y = (unsigned)f2bf(a.z) | ((unsigned)f2bf(a.w) << 16);
        u.z = (unsigned)f2bf(b.x) | ((unsigned)f2bf(b.y) << 16);
        u.w = (unsigned)f2bf(b.z) | ((unsigned)f2bf(b.w) << 16);
        *(uint4*)(nb + (t >> 5) * 256 + (t & 31) * 8) = u;
        return;
    }
    // ---- weight prep: one block per K-slab, LDS transpose ----
    const int slab = p - 2048;           // 0..23
    const int n = tid;                   // 0..255
#pragma unroll
    for (int kk = 0; kk < 32; ++kk) {
        const int k = slab * 32 + kk;    // 0..255 w_t, 256..511 w_r, 512..767 w_l
        const float* s = (k < 256) ? wt : ((k < 512) ? wrp : wl);
        T[n * 40 + kk] = f2bf(s[(k & 255) * OO + n]);
    }
    __syncthreads();
    uint4* dst = (uint4*)(wsb + slab * 8192 + n * 32);
    const uint4* src = (const uint4*)&T[n * 40];
#pragma unroll
    for (int q = 0; q < 4; ++q) dst[q] = src[q];
}

// ---------------------------------------------------------------------------
// Kernel 1: fused gather + GEMM + epilogue. 512 blocks x 256 thr (2/CU).
// Block -> 32 node rows (XCD-local) x all 256 cols.
// ---------------------------------------------------------------------------
__global__ __launch_bounds__(256, 2) void tbcnn_fused(
    const int* __restrict__ children, const unsigned short* __restrict__ nb,
    const unsigned short* __restrict__ wsb, const float* __restrict__ conv,
    float* __restrict__ out) {

    __shared__ unsigned short A2[32 * A2STR];    // 33,280 B: k'=k-256 in [0,512)

    const int tid  = threadIdx.x;
    const int wave = tid >> 6;
    const int lane = tid & 63;
    const int x = blockIdx.x & 7;                // XCD (dispatch round-robin)
    const int q = blockIdx.x >> 3;               // 0..63
    const int rbase = x * 2048 + q * 32;         // 32 rows, produced on XCD x

    // ---------------- Phase 1: gather -> LDS (8 nodes per wave) -------------
#pragma unroll 2
    for (int i = 0; i < 8; ++i) {
        const int m  = wave * 8 + i;             // local row 0..31
        const int nf = __builtin_amdgcn_readfirstlane(rbase + m);
        const int brow = nf & ~511;              // b*512
        const int* chp = children + (nf << 4);
        int cj[CC];
#pragma unroll
        for (int j = 0; j < CC; ++j) cj[j] = chp[j];     // scalar loads
        int ns = 0;
#pragma unroll
        for (int j = 0; j < CC; ++j) ns += (cj[j] != 0) ? 1 : 0;
        const float inv_den = (ns > 1) ? 1.0f / (float)(ns - 1) : 0.0f;
        const bool single = (ns == 1);

        uint2 ec[CC];                            // 16 child rows, 8 B/lane
#pragma unroll
        for (int j = 0; j < CC; ++j)
            ec[j] = *(const uint2*)(nb + (size_t)(brow + cj[j]) * 256 + lane * 4);

        float4 ar = make_float4(0.f, 0.f, 0.f, 0.f);
        float4 as = make_float4(0.f, 0.f, 0.f, 0.f);
#pragma unroll
        for (int j = 0; j < CC; ++j) {
            const float hasf = (cj[j] != 0) ? 1.0f : 0.0f;
            const float crr = single ? ((j == 0) ? 0.5f : 0.0f)
                                     : (float)j * inv_den;
            const float cr = crr * hasf;
            const float e0 = __builtin_bit_cast(float, ec[j].x << 16);
            const float e1 = __builtin_bit_cast(float, ec[j].x & 0xFFFF0000u);
            const float e2 = __builtin_bit_cast(float, ec[j].y << 16);
            const float e3 = __builtin_bit_cast(float, ec[j].y & 0xFFFF0000u);
            ar.x += cr * e0;   ar.y += cr * e1;   ar.z += cr * e2;   ar.w += cr * e3;
            as.x += hasf * e0; as.y += hasf * e1; as.z += hasf * e2; as.w += hasf * e3;
        }
        unsigned short* rowp = &A2[m * A2STR];
        uint2 v;
        v.x = (unsigned)f2bf(ar.x) | ((unsigned)f2bf(ar.y) << 16);
        v.y = (unsigned)f2bf(ar.z) | ((unsigned)f2bf(ar.w) << 16);
        *(uint2*)(rowp + lane * 4) = v;                          // k' 0..255: w_r
        v.x = (unsigned)f2bf(as.x - ar.x) | ((unsigned)f2bf(as.y - ar.y) << 16);
        v.y = (unsigned)f2bf(as.z - ar.z) | ((unsigned)f2bf(as.w - ar.w) << 16);
        *(uint2*)(rowp + 256 + lane * 4) = v;                    // k' 256..511: w_l
    }
    __syncthreads();

    // ---------------- Phase 2: MFMA K-loop ----------------------------------
    const int quad = lane >> 4;
    const int l16  = lane & 15;
    f32x4 acc[2][4];
#pragma unroll
    for (int mi = 0; mi < 2; ++mi)
#pragma unroll
        for (int ni = 0; ni < 4; ++ni)
            acc[mi][ni] = (f32x4){0.f, 0.f, 0.f, 0.f};

    // B fragment base: col = wave*64 + ni*16 + l16 (1 KB coalesced per load)
    const unsigned short* bbase = wsb + (wave * 64 + l16) * 32 + quad * 8;
    // A parent frags (slabs 0..7): nb rows rbase+mi*16+l16, k = s*32+quad*8
    const unsigned short* aG = nb + (size_t)(rbase + l16) * 256 + quad * 8;
    // A LDS frags (slabs 8..23)
    const unsigned short* aL = &A2[l16 * A2STR + quad * 8];

#pragma unroll 2
    for (int s = 0; s < 8; ++s) {
        bf16x8 af[2], bf[4];
        af[0] = *(const bf16x8*)(aG + s * 32);
        af[1] = *(const bf16x8*)(aG + 16 * 256 + s * 32);
#pragma unroll
        for (int ni = 0; ni < 4; ++ni)
            bf[ni] = *(const bf16x8*)(bbase + s * 8192 + ni * 512);
#pragma unroll
        for (int mi = 0; mi < 2; ++mi)
#pragma unroll
            for (int ni = 0; ni < 4; ++ni)
                acc[mi][ni] = __builtin_amdgcn_mfma_f32_16x16x32_bf16(
                    af[mi], bf[ni], acc[mi][ni], 0, 0, 0);
    }
#pragma unroll 2
    for (int s = 8; s < 24; ++s) {
        bf16x8 af[2], bf[4];
        af[0] = *(const bf16x8*)(aL + (s - 8) * 32);
        af[1] = *(const bf16x8*)(aL + 16 * A2STR + (s - 8) * 32);
#pragma unroll
        for (int ni = 0; ni < 4; ++ni)
            bf[ni] = *(const bf16x8*)(bbase + s * 8192 + ni * 512);
#pragma unroll
        for (int mi = 0; mi < 2; ++mi)
#pragma unroll
            for (int ni = 0; ni < 4; ++ni)
                acc[mi][ni] = __builtin_amdgcn_mfma_f32_16x16x32_bf16(
                    af[mi], bf[ni], acc[mi][ni], 0, 0, 0);
    }

    // ---------------- Epilogue: + conv, leaky_relu(0.01), fp32 store --------
#pragma unroll
    for (int ni = 0; ni < 4; ++ni) {
        const int col = wave * 64 + ni * 16 + l16;
        const float cv = conv[col];
#pragma unroll
        for (int mi = 0; mi < 2; ++mi) {
#pragma unroll
            for (int r = 0; r < 4; ++r) {
                const int row = rbase + mi * 16 + quad * 4 + r;
                float v = acc[mi][ni][r] + cv;
                v = (v > 0.f) ? v : 0.01f * v;
                out[(size_t)row * OO + col] = v;
            }
        }
    }
}

extern "C" void kernel_launch(void* const* d_in, const int* in_sizes, int n_in,
                              void* d_out, int out_size, void* d_ws, size_t ws_size,
                              hipStream_t stream) {
    // setup_inputs order: nodes, w_t, w_l, w_r, conv, children
    const float* nodes    = (const float*)d_in[0];
    const float* w_t      = (const float*)d_in[1];
    const float* w_l      = (const float*)d_in[2];
    const float* w_r      = (const float*)d_in[3];
    const float* conv     = (const float*)d_in[4];
    const int*   children = (const int*)d_in[5];

    unsigned short* nb  = (unsigned short*)d_ws;          // 8,388,608 B
    unsigned short* wsb = nb + NB_ELS;                    // +  393,216 B

    prep<<<2048 + 24, 256, 0, stream>>>(nodes, w_t, w_r, w_l, nb, wsb);
    tbcnn_fused<<<512, 256, 0, stream>>>(children, nb, wsb, conv, (float*)d_out);
}